// Round 1
// baseline (310.405 us; speedup 1.0000x reference)
//
#include <hip/hip_runtime.h>
#include <math.h>

#define NB    256
#define NC    3
#define NH    224
#define NW    224
#define SAMPLE_ELEMS (NC * NH * NW)            // 150528
#define SAMPLE_V4    (SAMPLE_ELEMS / 4)        // 37632
#define BLOCKS_PER_SAMPLE 8
#define CHUNK_V4 (SAMPLE_V4 / BLOCKS_PER_SAMPLE)  // 4704
#define W4 (NW / 4)                            // 56

struct SampleParams {
    float s;      // combined scale  (bsc * csc)
    float t;      // combined offset (mean_after * (1 - csc))
    int   flip;
    int   em;     // erase enabled
    int   ph, ph_end, pw, pw_end;
};

// ---------- Pass 1: per-sample partial sums (deterministic, no atomics) ----
__global__ __launch_bounds__(256) void sum_kernel(const float4* __restrict__ x,
                                                  float* __restrict__ partials) {
    const int b = blockIdx.x / BLOCKS_PER_SAMPLE;
    const int j = blockIdx.x % BLOCKS_PER_SAMPLE;
    const float4* base = x + (size_t)b * SAMPLE_V4 + (size_t)j * CHUNK_V4;

    float s = 0.0f;
    for (int k = threadIdx.x; k < CHUNK_V4; k += 256) {
        float4 v = base[k];
        s += (v.x + v.y) + (v.z + v.w);
    }
    // wave (64-lane) shuffle reduction, then LDS across the 4 waves
    #pragma unroll
    for (int off = 32; off > 0; off >>= 1) s += __shfl_down(s, off, 64);

    __shared__ float red[4];
    const int lane = threadIdx.x & 63;
    const int wid  = threadIdx.x >> 6;
    if (lane == 0) red[wid] = s;
    __syncthreads();
    if (threadIdx.x == 0)
        partials[blockIdx.x] = (red[0] + red[1]) + (red[2] + red[3]);
}

// ---------- Pass 1b: fold partials into per-sample affine + box params -----
__global__ __launch_bounds__(256) void params_kernel(
        const float* __restrict__ partials,
        const float* __restrict__ flip_u,
        const float* __restrict__ bright_u,
        const float* __restrict__ bright_v,
        const float* __restrict__ contrast_u,
        const float* __restrict__ contrast_v,
        const float* __restrict__ erase_u,
        const float* __restrict__ erase_box,
        SampleParams* __restrict__ prm) {
    const int b = threadIdx.x;  // one thread per sample, 256 threads

    float sum = 0.0f;
    #pragma unroll
    for (int j = 0; j < BLOCKS_PER_SAMPLE; ++j) sum += partials[b * BLOCKS_PER_SAMPLE + j];

    const float bsc  = (bright_u[b] < 0.7f) ? (0.8f + 0.4f * bright_v[b]) : 1.0f;
    const float mean = (sum / (float)SAMPLE_ELEMS) * bsc;   // mean of post-brightness image

    float csc, t;
    if (contrast_u[b] < 0.7f) {
        csc = 0.8f + 0.4f * contrast_v[b];
        t   = mean * (1.0f - csc);          // (x-m)*c + m == x*c + m*(1-c)
    } else {
        csc = 1.0f;
        t   = 0.0f;
    }

    SampleParams p;
    p.s    = bsc * csc;
    p.t    = t;
    p.flip = (flip_u[b] < 0.5f) ? 1 : 0;
    p.em   = (erase_u[b] < 0.3f) ? 1 : 0;

    // replicate reference f32 floor arithmetic exactly
    const float u0 = erase_box[b * 4 + 0];
    const float u1 = erase_box[b * 4 + 1];
    const float u2 = erase_box[b * 4 + 2];
    const float u3 = erase_box[b * 4 + 3];
    const int eh = (int)floorf((float)NH * (0.02f + 0.18f * u0));
    const int ew = (int)floorf((float)NW * (0.02f + 0.18f * u1));
    const int ph = (int)floorf((float)(NH - eh) * u2);
    const int pw = (int)floorf((float)(NW - ew) * u3);
    p.ph = ph; p.ph_end = ph + eh;
    p.pw = pw; p.pw_end = pw + ew;

    prm[b] = p;
}

// ---------- Pass 2: fused flip + affine + erase + clip, one float4/thread --
__global__ __launch_bounds__(256) void apply_kernel(const float* __restrict__ x,
                                                    const SampleParams* __restrict__ prm,
                                                    float* __restrict__ out) {
    const int i   = blockIdx.x * 256 + threadIdx.x;   // float4 index
    const int w4  = i % W4;
    const int row = i / W4;                            // b*NC*NH + c*NH + h
    const int h   = row % NH;
    const int b   = row / (NC * NH);

    const SampleParams p = prm[b];   // uniform per block (147 blocks/sample exactly)

    const int    w0      = w4 * 4;
    const float* src_row = x + (size_t)row * NW;

    float4 v;
    if (p.flip) {
        const float4 r = *(const float4*)(src_row + (NW - 4 - w0));
        v = make_float4(r.w, r.z, r.y, r.x);
    } else {
        v = *(const float4*)(src_row + w0);
    }

    const float s = p.s, t = p.t;
    float o0 = v.x * s + t;
    float o1 = v.y * s + t;
    float o2 = v.z * s + t;
    float o3 = v.w * s + t;

    if (p.em && h >= p.ph && h < p.ph_end) {
        if (w0     >= p.pw && w0     < p.pw_end) o0 = 0.0f;
        if (w0 + 1 >= p.pw && w0 + 1 < p.pw_end) o1 = 0.0f;
        if (w0 + 2 >= p.pw && w0 + 2 < p.pw_end) o2 = 0.0f;
        if (w0 + 3 >= p.pw && w0 + 3 < p.pw_end) o3 = 0.0f;
    }

    o0 = fminf(fmaxf(o0, 0.0f), 1.0f);
    o1 = fminf(fmaxf(o1, 0.0f), 1.0f);
    o2 = fminf(fmaxf(o2, 0.0f), 1.0f);
    o3 = fminf(fmaxf(o3, 0.0f), 1.0f);

    ((float4*)out)[i] = make_float4(o0, o1, o2, o3);
}

extern "C" void kernel_launch(void* const* d_in, const int* in_sizes, int n_in,
                              void* d_out, int out_size, void* d_ws, size_t ws_size,
                              hipStream_t stream) {
    const float* x          = (const float*)d_in[0];
    const float* flip_u     = (const float*)d_in[1];
    const float* bright_u   = (const float*)d_in[2];
    const float* bright_v   = (const float*)d_in[3];
    const float* contrast_u = (const float*)d_in[4];
    const float* contrast_v = (const float*)d_in[5];
    const float* erase_u    = (const float*)d_in[6];
    const float* erase_box  = (const float*)d_in[7];
    float* out = (float*)d_out;

    // workspace layout: [0, 8KB) partial sums, [8KB, 16KB) SampleParams
    float*        partials = (float*)d_ws;
    SampleParams* prm      = (SampleParams*)((char*)d_ws + NB * BLOCKS_PER_SAMPLE * sizeof(float));

    sum_kernel<<<NB * BLOCKS_PER_SAMPLE, 256, 0, stream>>>((const float4*)x, partials);
    params_kernel<<<1, 256, 0, stream>>>(partials, flip_u, bright_u, bright_v,
                                         contrast_u, contrast_v, erase_u, erase_box, prm);

    const int total_v4 = NB * SAMPLE_V4;              // 9,633,792
    apply_kernel<<<total_v4 / 256, 256, 0, stream>>>(x, prm, out);
}